// Round 1
// 1267.183 us; speedup vs baseline: 1.1515x; 1.1515x over previous
//
#include <hip/hip_runtime.h>

typedef unsigned short u16;
typedef unsigned int u32;

#define NPTS 131072
#define CD 128
#define KOFF 27
#define MMAP 65536
#define LDAB 136   // LDS row stride (u16) for A/B tiles: 128+8
#define LDC 132    // LDS row stride (u16) for C repack: keeps store banks <=2-way

__device__ __forceinline__ u16 f2bf(float f) {  // f32 -> bf16 RNE
  u32 u = __float_as_uint(f);
  u32 r = (u + 0x7fffu + ((u >> 16) & 1u)) >> 16;
  return (u16)r;
}

typedef __attribute__((ext_vector_type(8))) short bf16x8;
typedef __attribute__((ext_vector_type(4))) float f32x4;

// ---------------- dtype conversion ----------------
__global__ __launch_bounds__(256) void k_convert_x(const float* __restrict__ x,
                                                   u16* __restrict__ xb) {
  long i = ((long)blockIdx.x * 256 + threadIdx.x) * 8;
  float4 a = *(const float4*)(x + i);
  float4 b = *(const float4*)(x + i + 4);
  uint4 v;
  v.x = f2bf(a.x) | ((u32)f2bf(a.y) << 16);
  v.y = f2bf(a.z) | ((u32)f2bf(a.w) << 16);
  v.z = f2bf(b.x) | ((u32)f2bf(b.y) << 16);
  v.w = f2bf(b.z) | ((u32)f2bf(b.w) << 16);
  *(uint4*)(xb + i) = v;
}

// W [K][ci][co] f32 -> Wb [K][co][ci] bf16
__global__ __launch_bounds__(256) void k_convert_w(const float* __restrict__ W,
                                                   u16* __restrict__ Wb) {
  int idx = blockIdx.x * 256 + threadIdx.x;
  if (idx >= KOFF * 2048) return;
  int k = idx >> 11;
  int rem = idx & 2047;
  int co = rem >> 4;
  int cc = rem & 15;
  const float* ws = W + (long)k * (CD * CD) + (long)(cc * 8) * CD + co;
  u16 t[8];
#pragma unroll
  for (int j = 0; j < 8; ++j) t[j] = f2bf(ws[j * CD]);
  uint4 v;
  v.x = t[0] | ((u32)t[1] << 16);
  v.y = t[2] | ((u32)t[3] << 16);
  v.z = t[4] | ((u32)t[5] << 16);
  v.w = t[6] | ((u32)t[7] << 16);
  ((uint4*)Wb)[idx] = v;
}

// ---------------- counting sort (per k-group) by output row ----------------
__global__ __launch_bounds__(256) void k_hist(const int* __restrict__ mo,
                                              u32* __restrict__ hist) {
  int i = blockIdx.x * 256 + threadIdx.x;  // grid exact cnt/256
  atomicAdd(&hist[mo[i]], 1u);
}

__global__ __launch_bounds__(256) void k_scanA(const u32* __restrict__ hist,
                                               u32* __restrict__ offs,
                                               u32* __restrict__ bsum) {
  __shared__ u32 sh[256];
  int t = threadIdx.x, b = blockIdx.x, i = b * 256 + t;
  u32 v = hist[i];
  u32 run = v;
  sh[t] = run;
  __syncthreads();
  for (int d = 1; d < 256; d <<= 1) {
    u32 y = (t >= d) ? sh[t - d] : 0u;
    __syncthreads();
    run += y;
    sh[t] = run;
    __syncthreads();
  }
  offs[i] = run - v;
  if (t == 255) bsum[b] = run;
}

__global__ __launch_bounds__(512) void k_scanB(u32* __restrict__ bsum) {
  __shared__ u32 sh[512];
  int t = threadIdx.x;
  u32 v = bsum[t];
  u32 run = v;
  sh[t] = run;
  __syncthreads();
  for (int d = 1; d < 512; d <<= 1) {
    u32 y = (t >= d) ? sh[t - d] : 0u;
    __syncthreads();
    run += y;
    sh[t] = run;
    __syncthreads();
  }
  bsum[t] = run - v;
}

__global__ __launch_bounds__(256) void k_scanC(u32* __restrict__ offs,
                                               const u32* __restrict__ bsum, u32 cnt) {
  int t = threadIdx.x, b = blockIdx.x, i = b * 256 + t;
  offs[i] += bsum[b];
  if (i == 0) offs[NPTS] = cnt;
}

// rank[e] = final position of entry e's contribution (sequential write, low-contention atomics)
__global__ __launch_bounds__(256) void k_rank(const int* __restrict__ mo,
                                              const u32* __restrict__ offs,
                                              u32* __restrict__ cur,
                                              u32* __restrict__ rank) {
  int i = blockIdx.x * 256 + threadIdx.x;
  int o = mo[i];
  rank[i] = offs[o] + atomicAdd(&cur[o], 1u);
}

// ---------------- gather-GEMM, natural (k, m-tile) order, rank-scatter rows ----------------
__global__ __launch_bounds__(256) void k_gemm3(const u16* __restrict__ src,
                                               const u16* __restrict__ Wb,
                                               const int* __restrict__ mi,   // group base
                                               const u32* __restrict__ rank, // group-local
                                               u16* __restrict__ contrib,
                                               int kbase) {
  __shared__ u16 As[64 * LDAB];
  __shared__ u16 Bs[128 * LDAB];
  __shared__ u32 sin[64];
  __shared__ u32 srow[64];
  const int t = threadIdx.x;
  const int b = blockIdx.x;
  const int klocal = b >> 10;
  const int i0 = klocal * MMAP + (b & 1023) * 64;

  if (t < 64) {
    sin[t] = (u32)mi[i0 + t];
    srow[t] = rank[i0 + t];
  }
  const uint4* wsrc = (const uint4*)(Wb + (long)(kbase + klocal) * (CD * CD));
#pragma unroll
  for (int i = 0; i < 8; ++i) {
    int q = i * 256 + t;
    int co = q >> 4, cc = q & 15;
    *(uint4*)&Bs[co * LDAB + cc * 8] = wsrc[q];
  }
  __syncthreads();
#pragma unroll
  for (int i = 0; i < 4; ++i) {
    int q = i * 256 + t;
    int r = q >> 4, cc = q & 15;
    long row = sin[r];
    *(uint4*)&As[r * LDAB + cc * 8] = ((const uint4*)(src + row * CD))[cc];
  }
  __syncthreads();

  const int wave = t >> 6, lane = t & 63;
  const int lr = lane & 15, quad = lane >> 4;
  const int wm = (wave & 1) * 32;
  const int wn = (wave >> 1) * 64;
  f32x4 acc[2][4] = {};
#pragma unroll
  for (int kk = 0; kk < 4; ++kk) {
    bf16x8 a[2], bfr[4];
#pragma unroll
    for (int mt = 0; mt < 2; ++mt)
      a[mt] = *(const bf16x8*)&As[(wm + mt * 16 + lr) * LDAB + (kk * 4 + quad) * 8];
#pragma unroll
    for (int nt = 0; nt < 4; ++nt)
      bfr[nt] = *(const bf16x8*)&Bs[(wn + nt * 16 + lr) * LDAB + (kk * 4 + quad) * 8];
#pragma unroll
    for (int mt = 0; mt < 2; ++mt)
#pragma unroll
      for (int nt = 0; nt < 4; ++nt)
        acc[mt][nt] = __builtin_amdgcn_mfma_f32_16x16x32_bf16(a[mt], bfr[nt], acc[mt][nt], 0, 0, 0);
  }

  // repack C through LDS (C/D layout: col = lane&15, row = quad*4+reg), then coalesced row stores
  __syncthreads();
  u16* Cs = As;  // reuse: 64*132 u16 = 16.9KB <= As 17.4KB
#pragma unroll
  for (int mt = 0; mt < 2; ++mt)
#pragma unroll
    for (int v = 0; v < 4; ++v) {
      int slot = wm + mt * 16 + quad * 4 + v;
#pragma unroll
      for (int nt = 0; nt < 4; ++nt)
        Cs[slot * LDC + wn + nt * 16 + lr] = f2bf(acc[mt][nt][v]);
    }
  __syncthreads();
#pragma unroll
  for (int i = 0; i < 4; ++i) {
    int q = i * 256 + t;
    int r = q >> 4, cc = q & 15;
    size_t rk = srow[r];
    *(uint4*)(contrib + rk * CD + cc * 8) = *(const uint4*)&Cs[r * LDC + cc * 8];
  }
}

// ---------------- segmented reduce v4: 4 rows/wave, uint4 loads, shared offs preload ----------------
// wave W owns rows [16W, 16W+16); each 16-lane group handles one row (lane sub -> 8 channels).
// No per-row offs loads (17 offs preloaded once, distributed by shfl); acc writes of a batch of
// 4 consecutive rows form one contiguous 2KB store.
__global__ __launch_bounds__(256, 8) void k_segreduce4(const u16* __restrict__ contrib,
                                                       const u32* __restrict__ offs,
                                                       float* __restrict__ acc,
                                                       float* __restrict__ stats,
                                                       int first, int last) {
  __shared__ float sh[64][16];
  const int wave = threadIdx.x >> 6, lane = threadIdx.x & 63;
  const int W = blockIdx.x * 4 + wave;  // 8192 waves, 16 rows each
  const int g = lane >> 4, sub = lane & 15;
  const int r0 = W * 16;
  u32 ld_off = offs[r0 + (lane < 17 ? lane : 16)];
  float sx[8], sx2[8];
#pragma unroll
  for (int j = 0; j < 8; ++j) {
    sx[j] = 0.f;
    sx2[j] = 0.f;
  }
  for (int b = 0; b < 4; ++b) {
    const int row = r0 + b * 4 + g;
    const u32 s0 = __shfl(ld_off, b * 4 + g);
    const u32 s1 = __shfl(ld_off, b * 4 + g + 1);
    const int len = (int)(s1 - s0);
    int ml = len;
    ml = max(ml, __shfl_xor(ml, 16));
    ml = max(ml, __shfl_xor(ml, 32));
    float v[8];
#pragma unroll
    for (int j = 0; j < 8; ++j) v[j] = 0.f;
    const u32* cp = (const u32*)(contrib + (size_t)s0 * CD) + sub * 4;
    for (int i = 0; i < ml; ++i) {
      if (i < len) {
        uint4 d = *(const uint4*)(cp + (size_t)i * 64);
        v[0] += __uint_as_float(d.x << 16);
        v[1] += __uint_as_float(d.x & 0xffff0000u);
        v[2] += __uint_as_float(d.y << 16);
        v[3] += __uint_as_float(d.y & 0xffff0000u);
        v[4] += __uint_as_float(d.z << 16);
        v[5] += __uint_as_float(d.z & 0xffff0000u);
        v[6] += __uint_as_float(d.w << 16);
        v[7] += __uint_as_float(d.w & 0xffff0000u);
      }
    }
    float4* ap = (float4*)(acc + (size_t)row * CD + sub * 8);
    if (!first) {
      float4 p0 = ap[0], p1 = ap[1];
      v[0] += p0.x;
      v[1] += p0.y;
      v[2] += p0.z;
      v[3] += p0.w;
      v[4] += p1.x;
      v[5] += p1.y;
      v[6] += p1.z;
      v[7] += p1.w;
    }
    ap[0] = make_float4(v[0], v[1], v[2], v[3]);
    ap[1] = make_float4(v[4], v[5], v[6], v[7]);
    if (last) {
#pragma unroll
      for (int j = 0; j < 8; ++j) {
        sx[j] += v[j];
        sx2[j] += v[j] * v[j];
      }
    }
  }
  if (last) {
#pragma unroll
    for (int j = 0; j < 8; ++j) {
      sx[j] += __shfl_xor(sx[j], 16);
      sx[j] += __shfl_xor(sx[j], 32);
      sx2[j] += __shfl_xor(sx2[j], 16);
      sx2[j] += __shfl_xor(sx2[j], 32);
    }
    if (lane < 16) {
#pragma unroll
      for (int j = 0; j < 8; ++j) {
        sh[wave * 16 + sub][j] = sx[j];
        sh[wave * 16 + sub][8 + j] = sx2[j];
      }
    }
    __syncthreads();
    if (threadIdx.x < 128) {
      int c = threadIdx.x, sb = c >> 3, j = c & 7;
      float a = sh[sb][j] + sh[16 + sb][j] + sh[32 + sb][j] + sh[48 + sb][j];
      float q = sh[sb][8 + j] + sh[16 + sb][8 + j] + sh[32 + sb][8 + j] + sh[48 + sb][8 + j];
      atomicAdd(&stats[c], a);
      atomicAdd(&stats[128 + c], q);
    }
  }
}

// ---------------- BN finalize / apply ----------------
__global__ void k_finalize(const float* __restrict__ stats, const float* __restrict__ gamma,
                           const float* __restrict__ beta, float* __restrict__ scsh) {
  int c = threadIdx.x;
  float mean = stats[c] * (1.f / NPTS);
  float var = stats[128 + c] * (1.f / NPTS) - mean * mean;
  float sc = rsqrtf(var + 1e-5f) * gamma[c];
  scsh[c] = sc;
  scsh[128 + c] = beta[c] - mean * sc;
}

__device__ __forceinline__ float elu(float v) { return v > 0.f ? v : expf(v) - 1.f; }

__global__ __launch_bounds__(256) void k_apply_mid(const float* __restrict__ acc,
                                                   const float* __restrict__ scsh,
                                                   u16* __restrict__ y) {
  long i = ((long)blockIdx.x * 256 + threadIdx.x) * 4;
  int c = (int)(i & 127);
  float4 a = *(const float4*)(acc + i);
  float r0 = elu(a.x * scsh[c] + scsh[128 + c]);
  float r1 = elu(a.y * scsh[c + 1] + scsh[129 + c]);
  float r2 = elu(a.z * scsh[c + 2] + scsh[130 + c]);
  float r3 = elu(a.w * scsh[c + 3] + scsh[131 + c]);
  uint2 v;
  v.x = f2bf(r0) | ((u32)f2bf(r1) << 16);
  v.y = f2bf(r2) | ((u32)f2bf(r3) << 16);
  *(uint2*)(y + i) = v;
}

__global__ __launch_bounds__(256) void k_apply_final(const float* __restrict__ acc,
                                                     const float* __restrict__ scsh,
                                                     const float* __restrict__ x,
                                                     float* __restrict__ out) {
  long i = ((long)blockIdx.x * 256 + threadIdx.x) * 4;
  int c = (int)(i & 127);
  float4 a = *(const float4*)(acc + i);
  float4 rx = *(const float4*)(x + i);
  float4 o;
  o.x = elu(a.x * scsh[c] + scsh[128 + c] + rx.x);
  o.y = elu(a.y * scsh[c + 1] + scsh[129 + c] + rx.y);
  o.z = elu(a.z * scsh[c + 2] + scsh[130 + c] + rx.z);
  o.w = elu(a.w * scsh[c + 3] + scsh[131 + c] + rx.w);
  *(float4*)(out + i) = o;
}

// ---------------- host ----------------
extern "C" void kernel_launch(void* const* d_in, const int* in_sizes, int n_in,
                              void* d_out, int out_size, void* d_ws, size_t ws_size,
                              hipStream_t stream) {
  const float* x = (const float*)d_in[0];
  const float* W1 = (const float*)d_in[1];
  const float* g1 = (const float*)d_in[2];
  const float* b1 = (const float*)d_in[3];
  const float* W2 = (const float*)d_in[4];
  const float* g2 = (const float*)d_in[5];
  const float* b2 = (const float*)d_in[6];
  const int* m1i = (const int*)d_in[7];
  const int* m1o = (const int*)d_in[8];
  const int* m2i = (const int*)d_in[9];
  const int* m2o = (const int*)d_in[10];
  float* out = (float*)d_out;

  char* base = (char*)d_ws;
  size_t off = 0;
  auto alloc = [&](size_t bytes) -> void* {
    void* r = base + off;
    off = (off + bytes + 255) & ~(size_t)255;
    return r;
  };
  // xb doubles as the mid-activation buffer: after conv1's last GEMM, xb is dead,
  // so k_apply_mid writes the BN+ELU'd mid result back into it. Saves 32MB -> larger kcnt.
  u16* xb = (u16*)alloc((size_t)NPTS * CD * 2);
  u16* Wb1 = (u16*)alloc((size_t)KOFF * CD * CD * 2);
  u16* Wb2 = (u16*)alloc((size_t)KOFF * CD * CD * 2);
  float* acc = (float*)alloc((size_t)NPTS * CD * 4);
  // contiguous memset region: hist, cur
  u32* hist = (u32*)alloc((size_t)NPTS * 4);
  u32* cur = (u32*)alloc((size_t)NPTS * 4);
  size_t msSize = (size_t)((char*)base + off - (char*)hist);
  u32* offs = (u32*)alloc(((size_t)NPTS + 1) * 4);
  float* stats = (float*)alloc(256 * 4);
  float* scsh = (float*)alloc(256 * 4);
  u32* bsum = (u32*)alloc(512 * 4);

  // remaining ws -> k-group size (contrib 16.78MB + rank 0.26MB per k)
  size_t per_k = (size_t)MMAP * CD * 2 + (size_t)MMAP * 4 + 512;
  size_t avail = (ws_size > off + 4096) ? (ws_size - off - 4096) : 0;
  int kcnt = (int)(avail / per_k);
  if (kcnt < 1) kcnt = 1;
  if (kcnt > KOFF) kcnt = KOFF;
  u32* rank = (u32*)alloc((size_t)kcnt * MMAP * 4);
  u16* contrib = (u16*)alloc((size_t)kcnt * MMAP * CD * 2);

  k_convert_x<<<(NPTS * CD) / 2048, 256, 0, stream>>>(x, xb);
  k_convert_w<<<(KOFF * 2048 + 255) / 256, 256, 0, stream>>>(W1, Wb1);
  k_convert_w<<<(KOFF * 2048 + 255) / 256, 256, 0, stream>>>(W2, Wb2);

  auto run_conv = [&](const u16* srcm, const u16* Wbm, const int* mi, const int* mo) {
    hipMemsetAsync(stats, 0, 1024, stream);
    for (int g0 = 0; g0 < KOFF; g0 += kcnt) {
      int kc = (KOFF - g0 < kcnt) ? (KOFF - g0) : kcnt;
      u32 cnt = (u32)kc * MMAP;
      hipMemsetAsync(hist, 0, msSize, stream);
      k_hist<<<cnt / 256, 256, 0, stream>>>(mo + (long)g0 * MMAP, hist);
      k_scanA<<<512, 256, 0, stream>>>(hist, offs, bsum);
      k_scanB<<<1, 512, 0, stream>>>(bsum);
      k_scanC<<<512, 256, 0, stream>>>(offs, bsum, cnt);
      k_rank<<<cnt / 256, 256, 0, stream>>>(mo + (long)g0 * MMAP, offs, cur, rank);
      k_gemm3<<<kc * 1024, 256, 0, stream>>>(srcm, Wbm, mi + (long)g0 * MMAP, rank, contrib, g0);
      k_segreduce4<<<2048, 256, 0, stream>>>(contrib, offs, acc, stats,
                                             g0 == 0 ? 1 : 0, (g0 + kc == KOFF) ? 1 : 0);
    }
  };

  run_conv(xb, Wb1, m1i, m1o);
  k_finalize<<<1, 128, 0, stream>>>(stats, g1, b1, scsh);
  k_apply_mid<<<(NPTS * CD) / 1024, 256, 0, stream>>>(acc, scsh, xb);

  run_conv(xb, Wb2, m2i, m2o);
  k_finalize<<<1, 128, 0, stream>>>(stats, g2, b2, scsh);
  k_apply_final<<<(NPTS * CD) / 1024, 256, 0, stream>>>(acc, scsh, x, out);
}